// Round 8
// baseline (263.832 us; speedup 1.0000x reference)
//
#include <hip/hip_runtime.h>

#define LEAK 0.01f
#define BS 128           // nodes per bucket (dl fits in 7 bits)
#define PCHUNK 4096      // edges per chunk
#define PT 512           // unified block size
#define CT 512
#define MAXNB 256        // max buckets per graph
#define CPGMAX 256       // max chunks per graph

__device__ __forceinline__ float lrelu(float v) {
    return v >= 0.f ? v : LEAK * v;
}

__device__ __forceinline__ unsigned int fmin_encode(float x) {
    unsigned int u = __float_as_uint(x);
    return (u & 0x80000000u) ? ~u : (u | 0x80000000u);
}
__device__ __forceinline__ float fmin_decode(unsigned int k) {
    unsigned int u = (k & 0x80000000u) ? (k ^ 0x80000000u) : ~k;
    return __uint_as_float(u);
}

__device__ __forceinline__ unsigned int bf16_rne(float f) {
    unsigned int u = __float_as_uint(f);
    return (u + 0x7FFFu + ((u >> 16) & 1u)) >> 16;
}

__device__ __forceinline__ void block_add(float c, float* dst) {
    __shared__ float wsum[8];
#pragma unroll
    for (int off = 32; off > 0; off >>= 1) c += __shfl_down(c, off, 64);
    int lane = threadIdx.x & 63;
    int wave = threadIdx.x >> 6;
    if (lane == 0) wsum[wave] = c;
    __syncthreads();
    if (threadIdx.x == 0) {
        float s = 0.f;
        int nw = blockDim.x >> 6;
        for (int w = 0; w < nw; ++w) s += wsum[w];
        atomicAdd(dst, s);
    }
}

// ---------------------------------------------------------------------------
// phase bodies
// ---------------------------------------------------------------------------

__device__ __forceinline__ void init_body(
    const int* __restrict__ nf, const float* __restrict__ act,
    const float* __restrict__ W1, const float* __restrict__ b1,
    const float* __restrict__ lw, const float* __restrict__ lb,
    float* __restrict__ a1, unsigned short* __restrict__ a2,
    float* __restrict__ out, int N, int b, int ib) {
    int t = threadIdx.x;
    int n = ib * PT + t;
    float c = 0.f;
    if (n < N) {
        size_t i = (size_t)b * N + n;
        float x0 = (float)nf[i * 2 + 0];
        float x1 = (float)nf[i * 2 + 1];
        float x2 = act[i];
        float v1[8], v2[8];
#pragma unroll
        for (int j = 0; j < 8; ++j) {
            v1[j] = b1[j] + x0 * W1[0 * 8 + j] + x1 * W1[1 * 8 + j] + x2 * W1[2 * 8 + j];
            v2[j] =         x0 * W1[3 * 8 + j] + x1 * W1[4 * 8 + j] + x2 * W1[5 * 8 + j];
        }
        float4* o1 = (float4*)(a1 + i * 8);
        o1[0] = make_float4(v1[0], v1[1], v1[2], v1[3]);
        o1[1] = make_float4(v1[4], v1[5], v1[6], v1[7]);
        unsigned int w[4];
#pragma unroll
        for (int q = 0; q < 4; ++q)
            w[q] = bf16_rne(v2[2 * q]) | (bf16_rne(v2[2 * q + 1]) << 16);
        *(int4*)(a2 + i * 8) = make_int4(w[0], w[1], w[2], w[3]);
        c = x0 * lw[0] + x1 * lw[1] + x2 * lw[2];
        if (n == 0) c += lb[0];
    }
    block_add(c, &out[b]);
}

// pass A: per-chunk histogram of dst buckets -> cnt[c][bin]
__device__ __forceinline__ void count_body(
    const int* __restrict__ ei, int* __restrict__ cnt,
    int E, int NB, int CPG, int b, int c, int* __restrict__ lc) {
    int t = threadIdx.x;
    for (int i = t; i < NB; i += PT) lc[i] = 0;
    __syncthreads();
    int e0 = c * PCHUNK, end = min(e0 + PCHUNK, E);
    const int* drow = ei + (size_t)b * 2 * E + E;
    for (int e = e0 + t; e < end; e += PT)
        atomicAdd(&lc[drow[e] >> 7], 1);
    __syncthreads();
    int* crow = cnt + ((size_t)b * CPG + c) * NB;
    for (int i = t; i < NB; i += PT) crow[i] = lc[i];
}

// R8 prep: one block per graph. Hoists ALL the per-chunk offset math that
// R7's scatter recomputed 157x per graph (two 512-wide block scans + a
// 157-iteration column-sum loop = the 57us stall bill):
//   lstart_m[c][bin] = prefix over bins of cnt[c][:]   (within-chunk layout)
//   gbase_m[c][bin]  = gofs[bin] + sum_{c2<c} cnt[c2][bin]  (global dest)
//   gofs[bin]        = exclusive scan of bucket totals (for conv)
__global__ __launch_bounds__(PT) void prep_kernel(
    const int* __restrict__ cnt, int* __restrict__ lstart_m,
    int* __restrict__ gbase_m, int* __restrict__ gofs, int NB, int CPG) {
    __shared__ int ts[PT];
    int b = blockIdx.x;
    int t = threadIdx.x;
    const int* cb = cnt + (size_t)b * CPG * NB;
    int* lsb = lstart_m + (size_t)b * CPG * NB;
    int* gbb = gbase_m + (size_t)b * CPG * NB;

    // phase 1: row scans (prefix over bins) — thread = chunk
    for (int c = t; c < CPG; c += PT) {
        int run = 0;
        for (int bin = 0; bin < NB; ++bin) {
            int q = cb[(size_t)c * NB + bin];
            lsb[(size_t)c * NB + bin] = run;
            run += q;
        }
    }

    // phase 2a: column sums — thread = bin
    int full = 0;
    if (t < NB)
        for (int c = 0; c < CPG; ++c) full += cb[(size_t)c * NB + t];

    // phase 2b: block scan of full -> gofs
    int v = (t < NB) ? full : 0;
    ts[t] = v;
    __syncthreads();
    int incl = v;
    for (int off = 1; off < PT; off <<= 1) {
        int add = (t >= off) ? ts[t - off] : 0;
        __syncthreads();
        incl += add;
        ts[t] = incl;
        __syncthreads();
    }
    int excl = incl - v;
    if (t < NB) gofs[(size_t)b * (NB + 1) + t] = excl;
    if (t == PT - 1) gofs[(size_t)b * (NB + 1) + NB] = incl;

    // phase 2c: column running bases — thread = bin
    if (t < NB) {
        int run = excl;
        for (int c = 0; c < CPG; ++c) {
            gbb[(size_t)c * NB + t] = run;
            run += cb[(size_t)c * NB + t];
        }
    }
}

// pass B (R8): zero scans, zero column loops. Load two precomputed rows
// (coalesced 628B each), rank via LDS atomics, stage bin-sorted in LDS,
// stream out in contiguous runs.
__device__ __forceinline__ void scatter_body(
    const int* __restrict__ ei, const float* __restrict__ ea,
    const int* __restrict__ lstart_m, const int* __restrict__ gbase_m,
    int2* __restrict__ cpairs, int E, int NB, int CPG, int b, int c,
    int2* __restrict__ stg, int* __restrict__ lc, int* __restrict__ lstart,
    int* __restrict__ gbase) {
    int t = threadIdx.x;
    int e0 = c * PCHUNK, end = min(e0 + PCHUNK, E);
    const int* srow = ei + (size_t)b * 2 * E;
    const int* drow = srow + E;

    const int* lsr = lstart_m + ((size_t)b * CPG + c) * NB;
    const int* gbr = gbase_m + ((size_t)b * CPG + c) * NB;
    for (int i = t; i < NB; i += PT) {
        lstart[i] = lsr[i];
        gbase[i] = gbr[i];
        lc[i] = 0;
    }
    __syncthreads();

    // rank + stage into LDS (bin rides in bits 23..30; src 0-15; dl 16-22)
    // within-bin order is arbitrary: irrelevant for min-aggregation
#pragma unroll
    for (int j = 0; j < PCHUNK / PT; ++j) {
        int e = e0 + j * PT + t;
        if (e < end) {
            int d = drow[e];
            int bin = d >> 7;
            int r = atomicAdd(&lc[bin], 1);
            stg[lstart[bin] + r] =
                make_int2(srow[e] | ((d & 127) << 16) | (bin << 23),
                          __float_as_int(ea[(size_t)b * E + e]));
        }
    }
    __syncthreads();

    // stream staged buffer out: consecutive k -> contiguous dest per run
    int total = end - e0;
    int2* cp = cpairs + (size_t)b * E;
    for (int k = t; k < total; k += PT) {
        int2 pv = stg[k];
        int bin = (pv.x >> 23) & 255;
        cp[gbase[bin] + (k - lstart[bin])] = pv;
    }
}

__device__ __forceinline__ void conv_edge_compute(
    const float* we, const float* bb, const float* __restrict__ W2,
    int2 p, int4 raw, const float* __restrict__ a1s,
    unsigned int* __restrict__ acc) {
    int dl = (p.x >> 16) & 127;
    float eav = __int_as_float(p.y);
    unsigned int wq[4] = {(unsigned int)raw.x, (unsigned int)raw.y,
                          (unsigned int)raw.z, (unsigned int)raw.w};
    float a2v[8];
#pragma unroll
    for (int q = 0; q < 4; ++q) {
        a2v[2 * q]     = __uint_as_float(wq[q] << 16);
        a2v[2 * q + 1] = __uint_as_float(wq[q] & 0xFFFF0000u);
    }
    float h1[8];
#pragma unroll
    for (int j = 0; j < 8; ++j) {
        h1[j] = a1s[dl * 9 + j] + a2v[j];
        h1[j] = fmaf(eav, we[j], h1[j]);
        h1[j] = lrelu(h1[j]);
    }
    float h2[8];
#pragma unroll
    for (int j = 0; j < 8; ++j) h2[j] = bb[j];
#pragma unroll
    for (int kk = 0; kk < 8; ++kk) {
        float hk = h1[kk];
#pragma unroll
        for (int j = 0; j < 8; ++j) h2[j] = fmaf(hk, W2[kk * 8 + j], h2[j]);
    }
#pragma unroll
    for (int j = 0; j < 8; ++j)
        atomicMin(&acc[dl * 9 + j], fmin_encode(h2[j]));
}

// batch-4: 4 outstanding a2 gathers per wave iteration hide L2/L3 latency
__device__ __forceinline__ void conv_edges_dense(
    const unsigned short* __restrict__ a2g, const float* we, const float* bb,
    const float* __restrict__ W2, const int2* __restrict__ cpg,
    int start, int end,
    const float* __restrict__ a1s, unsigned int* __restrict__ acc) {
    int t = threadIdx.x;
    int k = start + t * 4;
    for (; k + 3 < end; k += CT * 4) {
        int2 p0 = cpg[k];
        int2 p1 = cpg[k + 1];
        int2 p2 = cpg[k + 2];
        int2 p3 = cpg[k + 3];
        int4 v0 = *(const int4*)(a2g + (size_t)(p0.x & 0xFFFF) * 8);
        int4 v1 = *(const int4*)(a2g + (size_t)(p1.x & 0xFFFF) * 8);
        int4 v2 = *(const int4*)(a2g + (size_t)(p2.x & 0xFFFF) * 8);
        int4 v3 = *(const int4*)(a2g + (size_t)(p3.x & 0xFFFF) * 8);
        conv_edge_compute(we, bb, W2, p0, v0, a1s, acc);
        conv_edge_compute(we, bb, W2, p1, v1, a1s, acc);
        conv_edge_compute(we, bb, W2, p2, v2, a1s, acc);
        conv_edge_compute(we, bb, W2, p3, v3, a1s, acc);
    }
    for (int e = k; e < end && e < k + 4; ++e) {
        int2 p = cpg[e];
        int4 v = *(const int4*)(a2g + (size_t)(p.x & 0xFFFF) * 8);
        conv_edge_compute(we, bb, W2, p, v, a1s, acc);
    }
}

__device__ __forceinline__ void conv_mid_body(
    const float* __restrict__ a1, const unsigned short* __restrict__ a2,
    const float* __restrict__ w1e, const float* __restrict__ W2,
    const float* __restrict__ b2,
    const float* __restrict__ nW1, const float* __restrict__ nb1,
    const int* __restrict__ gofs, const int2* __restrict__ cpairs,
    float* __restrict__ na1, unsigned short* __restrict__ na2,
    int N, int NB, int E, int b, int bin,
    float* __restrict__ a1s, unsigned int* __restrict__ acc) {
    int n0 = bin << 7;
    int nCnt = min(BS, N - n0);
    int t = threadIdx.x;
    size_t node0 = (size_t)b * N + n0;

    for (int i = t; i < nCnt * 8; i += CT)
        a1s[(i >> 3) * 9 + (i & 7)] = a1[node0 * 8 + i];
    for (int i = t; i < BS * 9; i += CT) acc[i] = 0xFFFFFFFFu;
    float we[8], bb[8];
#pragma unroll
    for (int j = 0; j < 8; ++j) { we[j] = w1e[j]; bb[j] = b2[j]; }
    const int* gofsb = gofs + (size_t)b * (NB + 1);
    int start = gofsb[bin];
    int end = gofsb[bin + 1];
    __syncthreads();

    conv_edges_dense(a2 + (size_t)b * N * 8, we, bb, W2,
                     cpairs + (size_t)b * E, start, end, a1s, acc);
    __syncthreads();

    for (int i = t; i < nCnt * 8; i += CT) {
        float v = fmin_decode(acc[(i >> 3) * 9 + (i & 7)]);
        unsigned int u = __float_as_uint(v);
        if ((u & 0x7F800000u) == 0x7F800000u) v = 0.f;
        a1s[(i >> 3) * 9 + (i & 7)] = lrelu(v);
    }
    __syncthreads();

    for (int nh = t; nh < nCnt * 2; nh += CT) {
        int node = nh >> 1, half = nh & 1;
        float h[8];
#pragma unroll
        for (int j = 0; j < 8; ++j) h[j] = a1s[node * 9 + j];
        float v[8];
#pragma unroll
        for (int j = 0; j < 8; ++j) v[j] = half ? 0.f : nb1[j];
        const float* Wbase = nW1 + (half ? 64 : 0);
#pragma unroll
        for (int k = 0; k < 8; ++k) {
            float hk = h[k];
#pragma unroll
            for (int j = 0; j < 8; ++j) v[j] = fmaf(hk, Wbase[k * 8 + j], v[j]);
        }
        if (half) {
            unsigned int w[4];
#pragma unroll
            for (int q = 0; q < 4; ++q)
                w[q] = bf16_rne(v[2 * q]) | (bf16_rne(v[2 * q + 1]) << 16);
            *(int4*)(na2 + (node0 + node) * 8) = make_int4(w[0], w[1], w[2], w[3]);
        } else {
            float4* o = (float4*)(na1 + (node0 + node) * 8);
            o[0] = make_float4(v[0], v[1], v[2], v[3]);
            o[1] = make_float4(v[4], v[5], v[6], v[7]);
        }
    }
    __syncthreads();
}

__device__ __forceinline__ void conv_final_body(
    const float* __restrict__ a1, const unsigned short* __restrict__ a2,
    const float* __restrict__ w1e, const float* __restrict__ W2,
    const float* __restrict__ b2, const float* __restrict__ lw,
    const int* __restrict__ gofs, const int2* __restrict__ cpairs,
    float* __restrict__ out, int N, int NB, int E, int b, int bin,
    float* __restrict__ a1s, unsigned int* __restrict__ acc) {
    int n0 = bin << 7;
    int nCnt = min(BS, N - n0);
    int t = threadIdx.x;
    size_t node0 = (size_t)b * N + n0;

    for (int i = t; i < nCnt * 8; i += CT)
        a1s[(i >> 3) * 9 + (i & 7)] = a1[node0 * 8 + i];
    for (int i = t; i < BS * 9; i += CT) acc[i] = 0xFFFFFFFFu;
    float we[8], bb[8];
#pragma unroll
    for (int j = 0; j < 8; ++j) { we[j] = w1e[j]; bb[j] = b2[j]; }
    const int* gofsb = gofs + (size_t)b * (NB + 1);
    int start = gofsb[bin];
    int end = gofsb[bin + 1];
    __syncthreads();

    conv_edges_dense(a2 + (size_t)b * N * 8, we, bb, W2,
                     cpairs + (size_t)b * E, start, end, a1s, acc);
    __syncthreads();

    float c = 0.f;
    if (t < nCnt) {
#pragma unroll
        for (int j = 0; j < 8; ++j) {
            float v = fmin_decode(acc[t * 9 + j]);
            unsigned int u = __float_as_uint(v);
            if ((u & 0x7F800000u) == 0x7F800000u) v = 0.f;
            c = fmaf(lrelu(v), lw[3 + j], c);
        }
    }
    __syncthreads();
    block_add(c, &out[b]);
}

// ---------------------------------------------------------------------------
// kernels
// ---------------------------------------------------------------------------

__global__ __launch_bounds__(PT) void count_init_kernel(
    const int* __restrict__ ei, int* __restrict__ cnt,
    const int* __restrict__ nf, const float* __restrict__ act,
    const float* __restrict__ W1, const float* __restrict__ b1,
    const float* __restrict__ lw, const float* __restrict__ lb,
    float* __restrict__ a1, unsigned short* __restrict__ a2,
    float* __restrict__ out, int E, int N, int NB, int CPG) {
    __shared__ int lc[MAXNB];
    int b = blockIdx.y;
    if (blockIdx.x >= CPG) {
        init_body(nf, act, W1, b1, lw, lb, a1, a2, out, N, b, blockIdx.x - CPG);
        return;
    }
    count_body(ei, cnt, E, NB, CPG, b, blockIdx.x, lc);
}

__global__ __launch_bounds__(PT) void scatter_kernel(
    const int* __restrict__ ei, const float* __restrict__ ea,
    const int* __restrict__ lstart_m, const int* __restrict__ gbase_m,
    int2* __restrict__ cpairs, int E, int NB, int CPG) {
    __shared__ __align__(16) int2 stg[PCHUNK];
    __shared__ int lc[MAXNB];
    __shared__ int lstart[MAXNB];
    __shared__ int gbase[MAXNB];
    scatter_body(ei, ea, lstart_m, gbase_m, cpairs, E, NB, CPG,
                 blockIdx.y, blockIdx.x, stg, lc, lstart, gbase);
}

__global__ __launch_bounds__(CT) void conv_mid_kernel(
    const float* __restrict__ a1, const unsigned short* __restrict__ a2,
    const float* __restrict__ w1e, const float* __restrict__ W2,
    const float* __restrict__ b2,
    const float* __restrict__ nW1, const float* __restrict__ nb1,
    const int* __restrict__ gofs, const int2* __restrict__ cpairs,
    float* __restrict__ na1, unsigned short* __restrict__ na2,
    int N, int NB, int E) {
    __shared__ float a1s[BS * 9];
    __shared__ unsigned int acc[BS * 9];
    conv_mid_body(a1, a2, w1e, W2, b2, nW1, nb1, gofs, cpairs, na1, na2,
                  N, NB, E, blockIdx.y, blockIdx.x, a1s, acc);
}

__global__ __launch_bounds__(CT) void conv_final_kernel(
    const float* __restrict__ a1, const unsigned short* __restrict__ a2,
    const float* __restrict__ w1e, const float* __restrict__ W2,
    const float* __restrict__ b2, const float* __restrict__ lw,
    const int* __restrict__ gofs, const int2* __restrict__ cpairs,
    float* __restrict__ out, int N, int NB, int E) {
    __shared__ float a1s[BS * 9];
    __shared__ unsigned int acc[BS * 9];
    conv_final_body(a1, a2, w1e, W2, b2, lw, gofs, cpairs, out,
                    N, NB, E, blockIdx.y, blockIdx.x, a1s, acc);
}

// ---------------------------------------------------------------------------
// atomic fallback (proven path)
// ---------------------------------------------------------------------------

__global__ __launch_bounds__(256) void node_init_kernel(
    const int* __restrict__ nf, const float* __restrict__ act,
    float* __restrict__ x0, int BN) {
    int tid = blockIdx.x * blockDim.x + threadIdx.x;
    if (tid >= BN) return;
    x0[tid * 3 + 0] = (float)nf[tid * 2 + 0];
    x0[tid * 3 + 1] = (float)nf[tid * 2 + 1];
    x0[tid * 3 + 2] = act[tid];
}

template <int D>
__global__ __launch_bounds__(256) void edge_conv_kernel(
    const float* __restrict__ x, const int* __restrict__ ei,
    const float* __restrict__ ea,
    const float* __restrict__ W1, const float* __restrict__ b1,
    const float* __restrict__ W2, const float* __restrict__ b2,
    unsigned int* __restrict__ agg, int E, int N, int B) {
    int tid = blockIdx.x * blockDim.x + threadIdx.x;
    if (tid >= B * E) return;
    int b = tid / E;
    int e = tid - b * E;
    const int* eb = ei + (size_t)b * 2 * E;
    int s = eb[e];
    int d = eb[E + e];
    const float* xi = x + ((size_t)b * N + d) * D;
    const float* xj = x + ((size_t)b * N + s) * D;
    constexpr int M = 2 * D + 1;
    float m[M];
#pragma unroll
    for (int k = 0; k < D; ++k) { m[k] = xi[k]; m[D + k] = xj[k]; }
    m[2 * D] = ea[(size_t)b * E + e];
    float h1[8];
#pragma unroll
    for (int j = 0; j < 8; ++j) h1[j] = b1[j];
#pragma unroll
    for (int k = 0; k < M; ++k) {
        float mk = m[k];
#pragma unroll
        for (int j = 0; j < 8; ++j) h1[j] = fmaf(mk, W1[k * 8 + j], h1[j]);
    }
#pragma unroll
    for (int j = 0; j < 8; ++j) h1[j] = lrelu(h1[j]);
    float h2[8];
#pragma unroll
    for (int j = 0; j < 8; ++j) h2[j] = b2[j];
#pragma unroll
    for (int k = 0; k < 8; ++k) {
        float hk = h1[k];
#pragma unroll
        for (int j = 0; j < 8; ++j) h2[j] = fmaf(hk, W2[k * 8 + j], h2[j]);
    }
    unsigned int* ag = agg + ((size_t)b * N + d) * 8;
#pragma unroll
    for (int j = 0; j < 8; ++j) atomicMin(&ag[j], fmin_encode(h2[j]));
}

__global__ __launch_bounds__(256) void finalize_kernel(
    unsigned int* __restrict__ agg, int total) {
    int tid = blockIdx.x * blockDim.x + threadIdx.x;
    if (tid >= total) return;
    float v = fmin_decode(agg[tid]);
    unsigned int u = __float_as_uint(v);
    if ((u & 0x7F800000u) == 0x7F800000u) v = 0.f;
    ((float*)agg)[tid] = lrelu(v);
}

__global__ __launch_bounds__(256) void pool_kernel(
    const float* __restrict__ x0, const float* __restrict__ h,
    const float* __restrict__ lw, const float* __restrict__ lb,
    float* __restrict__ out, int N) {
    int b = blockIdx.y;
    int n = blockIdx.x * blockDim.x + threadIdx.x;
    float c = 0.f;
    if (n < N) {
        const float* x = x0 + ((size_t)b * N + n) * 3;
        const float* hh = h + ((size_t)b * N + n) * 8;
        c = x[0] * lw[0] + x[1] * lw[1] + x[2] * lw[2];
#pragma unroll
        for (int k = 0; k < 8; ++k) c = fmaf(hh[k], lw[3 + k], c);
        if (n == 0) c += lb[0];
    }
    block_add(c, &out[b]);
}

// ---------------------------------------------------------------------------

static inline size_t align256(size_t x) { return (x + 255) & ~(size_t)255; }

extern "C" void kernel_launch(void* const* d_in, const int* in_sizes, int n_in,
                              void* d_out, int out_size, void* d_ws, size_t ws_size,
                              hipStream_t stream) {
    const int B = 4;
    const int N = in_sizes[1] / B;            // actions [B,N]
    const int E = in_sizes[2] / (2 * B);      // edge_index [B,2,E]

    const int*   nf  = (const int*)d_in[0];
    const float* act = (const float*)d_in[1];
    const int*   ei  = (const int*)d_in[2];   // int32 (JAX x64 disabled)
    const float* ea  = (const float*)d_in[3];
    const float* c1_W1 = (const float*)d_in[4];
    const float* c1_b1 = (const float*)d_in[5];
    const float* c1_W2 = (const float*)d_in[6];
    const float* c1_b2 = (const float*)d_in[7];
    const float* c2_W1 = (const float*)d_in[8];
    const float* c2_b1 = (const float*)d_in[9];
    const float* c2_W2 = (const float*)d_in[10];
    const float* c2_b2 = (const float*)d_in[11];
    const float* c3_W1 = (const float*)d_in[12];
    const float* c3_b1 = (const float*)d_in[13];
    const float* c3_W2 = (const float*)d_in[14];
    const float* c3_b2 = (const float*)d_in[15];
    const float* lw    = (const float*)d_in[16];
    const float* lb    = (const float*)d_in[17];
    float* out = (float*)d_out;

    const int BN = B * N;
    const int BE = B * E;
    const int NB = (N + BS - 1) / BS;
    const int CPG = (E + PCHUNK - 1) / PCHUNK;
    const int initBlocks = (N + PT - 1) / PT;

    // ---- workspace layout ----
    char* ws = (char*)d_ws;
    size_t off = 0;
    float* a1A = (float*)(ws + off);           off += align256((size_t)BN * 8 * 4);
    float* a1B = (float*)(ws + off);           off += align256((size_t)BN * 8 * 4);
    unsigned short* a2A = (unsigned short*)(ws + off); off += align256((size_t)BN * 8 * 2);
    unsigned short* a2B = (unsigned short*)(ws + off); off += align256((size_t)BN * 8 * 2);
    int* cnt      = (int*)(ws + off);  off += align256((size_t)B * CPG * NB * 4);
    int* lstart_m = (int*)(ws + off);  off += align256((size_t)B * CPG * NB * 4);
    int* gbase_m  = (int*)(ws + off);  off += align256((size_t)B * CPG * NB * 4);
    int2* cpairs = (int2*)(ws + off);  off += align256((size_t)BE * 8);
    int* gofs   = (int*)(ws + off);    off += align256((size_t)B * (NB + 1) * 4);
    float* x0   = (float*)(ws + off);  off += align256((size_t)BN * 3 * 4);
    const bool useFast = (off <= ws_size) && (NB <= MAXNB) && (CPG <= CPGMAX) &&
                         (N <= 32768);

    hipMemsetAsync(out, 0, (size_t)B * sizeof(float), stream);

    if (useFast) {
        dim3 pgrid(CPG + initBlocks, B);
        dim3 sgrid(CPG, B);
        dim3 cgrid(NB, B);
        count_init_kernel<<<pgrid, PT, 0, stream>>>(
            ei, cnt, nf, act, c1_W1, c1_b1, lw, lb, a1A, a2A, out,
            E, N, NB, CPG);
        prep_kernel<<<B, PT, 0, stream>>>(
            cnt, lstart_m, gbase_m, gofs, NB, CPG);
        scatter_kernel<<<sgrid, PT, 0, stream>>>(
            ei, ea, lstart_m, gbase_m, cpairs, E, NB, CPG);
        conv_mid_kernel<<<cgrid, CT, 0, stream>>>(
            a1A, a2A, c1_W1 + 6 * 8, c1_W2, c1_b2, c2_W1, c2_b1,
            gofs, cpairs, a1B, a2B, N, NB, E);
        conv_mid_kernel<<<cgrid, CT, 0, stream>>>(
            a1B, a2B, c2_W1 + 16 * 8, c2_W2, c2_b2, c3_W1, c3_b1,
            gofs, cpairs, a1A, a2A, N, NB, E);
        conv_final_kernel<<<cgrid, CT, 0, stream>>>(
            a1A, a2A, c3_W1 + 16 * 8, c3_W2, c3_b2, lw,
            gofs, cpairs, out, N, NB, E);
    } else {
        // ---- atomic fallback ----
        const int egrid = (BE + 255) / 256;
        const int aggTotal = BN * 8;
        const int agrid = (aggTotal + 255) / 256;
        const size_t aggBytes = (size_t)aggTotal * 4;
        unsigned int* uA = (unsigned int*)a1A;
        unsigned int* uB = (unsigned int*)a1B;

        node_init_kernel<<<(BN + 255) / 256, 256, 0, stream>>>(nf, act, x0, BN);

        hipMemsetAsync(uA, 0xFF, aggBytes, stream);
        edge_conv_kernel<3><<<egrid, 256, 0, stream>>>(
            x0, ei, ea, c1_W1, c1_b1, c1_W2, c1_b2, uA, E, N, B);
        finalize_kernel<<<agrid, 256, 0, stream>>>(uA, aggTotal);

        hipMemsetAsync(uB, 0xFF, aggBytes, stream);
        edge_conv_kernel<8><<<egrid, 256, 0, stream>>>(
            (const float*)uA, ei, ea, c2_W1, c2_b1, c2_W2, c2_b2, uB, E, N, B);
        finalize_kernel<<<agrid, 256, 0, stream>>>(uB, aggTotal);

        hipMemsetAsync(uA, 0xFF, aggBytes, stream);
        edge_conv_kernel<8><<<egrid, 256, 0, stream>>>(
            (const float*)uB, ei, ea, c3_W1, c3_b1, c3_W2, c3_b2, uA, E, N, B);
        finalize_kernel<<<agrid, 256, 0, stream>>>(uA, aggTotal);

        dim3 plgrid((N + 255) / 256, B);
        pool_kernel<<<plgrid, 256, 0, stream>>>(x0, (const float*)uA, lw, lb, out, N);
    }
}

// Round 9
// 199.580 us; speedup vs baseline: 1.3219x; 1.3219x over previous
//
#include <hip/hip_runtime.h>

#define LEAK 0.01f
#define BS 128           // nodes per bucket (dl fits in 7 bits)
#define PCHUNK 4096      // edges per chunk
#define PT 512           // unified block size
#define CT 512
#define MAXNB 256        // max buckets per graph
#define CPGMAX 256       // max chunks per graph

__device__ __forceinline__ float lrelu(float v) {
    return v >= 0.f ? v : LEAK * v;
}

__device__ __forceinline__ unsigned int fmin_encode(float x) {
    unsigned int u = __float_as_uint(x);
    return (u & 0x80000000u) ? ~u : (u | 0x80000000u);
}
__device__ __forceinline__ float fmin_decode(unsigned int k) {
    unsigned int u = (k & 0x80000000u) ? (k ^ 0x80000000u) : ~k;
    return __uint_as_float(u);
}

__device__ __forceinline__ unsigned int bf16_rne(float f) {
    unsigned int u = __float_as_uint(f);
    return (u + 0x7FFFu + ((u >> 16) & 1u)) >> 16;
}

__device__ __forceinline__ void block_add(float c, float* dst) {
    __shared__ float wsum[8];
#pragma unroll
    for (int off = 32; off > 0; off >>= 1) c += __shfl_down(c, off, 64);
    int lane = threadIdx.x & 63;
    int wave = threadIdx.x >> 6;
    if (lane == 0) wsum[wave] = c;
    __syncthreads();
    if (threadIdx.x == 0) {
        float s = 0.f;
        int nw = blockDim.x >> 6;
        for (int w = 0; w < nw; ++w) s += wsum[w];
        atomicAdd(dst, s);
    }
}

// ---------------------------------------------------------------------------
// phase bodies
// ---------------------------------------------------------------------------

__device__ __forceinline__ void init_body(
    const int* __restrict__ nf, const float* __restrict__ act,
    const float* __restrict__ W1, const float* __restrict__ b1,
    const float* __restrict__ lw, const float* __restrict__ lb,
    float* __restrict__ a1, unsigned short* __restrict__ a2,
    float* __restrict__ out, int N, int b, int ib) {
    int t = threadIdx.x;
    int n = ib * PT + t;
    float c = 0.f;
    if (n < N) {
        size_t i = (size_t)b * N + n;
        float x0 = (float)nf[i * 2 + 0];
        float x1 = (float)nf[i * 2 + 1];
        float x2 = act[i];
        float v1[8], v2[8];
#pragma unroll
        for (int j = 0; j < 8; ++j) {
            v1[j] = b1[j] + x0 * W1[0 * 8 + j] + x1 * W1[1 * 8 + j] + x2 * W1[2 * 8 + j];
            v2[j] =         x0 * W1[3 * 8 + j] + x1 * W1[4 * 8 + j] + x2 * W1[5 * 8 + j];
        }
        float4* o1 = (float4*)(a1 + i * 8);
        o1[0] = make_float4(v1[0], v1[1], v1[2], v1[3]);
        o1[1] = make_float4(v1[4], v1[5], v1[6], v1[7]);
        unsigned int w[4];
#pragma unroll
        for (int q = 0; q < 4; ++q)
            w[q] = bf16_rne(v2[2 * q]) | (bf16_rne(v2[2 * q + 1]) << 16);
        *(int4*)(a2 + i * 8) = make_int4(w[0], w[1], w[2], w[3]);
        c = x0 * lw[0] + x1 * lw[1] + x2 * lw[2];
        if (n == 0) c += lb[0];
    }
    block_add(c, &out[b]);
}

// pass A: per-chunk LDS histogram -> one atomicAdd per bin into per-graph
// totals gtot[b][bin]. (R9: no per-chunk cnt matrix anymore — runtime cursor
// allocation in scatter makes cross-chunk prefix math unnecessary, because
// min-aggregation is order-invariant within a bucket.)
__device__ __forceinline__ void count_body(
    const int* __restrict__ ei, int* __restrict__ gtot,
    int E, int NB, int CPG, int b, int c, int* __restrict__ lc) {
    int t = threadIdx.x;
    for (int i = t; i < NB; i += PT) lc[i] = 0;
    __syncthreads();
    int e0 = c * PCHUNK, end = min(e0 + PCHUNK, E);
    const int* drow = ei + (size_t)b * 2 * E + E;
    for (int e = e0 + t; e < end; e += PT)
        atomicAdd(&lc[drow[e] >> 7], 1);
    __syncthreads();
    int* grow = gtot + (size_t)b * NB;
    for (int i = t; i < NB; i += PT)
        if (lc[i] > 0) atomicAdd(&grow[i], lc[i]);
}

// R9 scan: one block per graph, one in-block scan of the NB bucket totals.
// Replaces R8's prep (79us: 4 blocks x serial 157-loops, 0.3% occupancy).
__global__ __launch_bounds__(PT) void scan_kernel(
    const int* __restrict__ gtot, int* __restrict__ gofs,
    int* __restrict__ gcursor, int NB) {
    __shared__ int ts[PT];
    int b = blockIdx.x;
    int t = threadIdx.x;
    int v = (t < NB) ? gtot[(size_t)b * NB + t] : 0;
    ts[t] = v;
    __syncthreads();
    int incl = v;
    for (int off = 1; off < PT; off <<= 1) {
        int add = (t >= off) ? ts[t - off] : 0;
        __syncthreads();
        incl += add;
        ts[t] = incl;
        __syncthreads();
    }
    int excl = incl - v;
    if (t < NB) {
        gofs[(size_t)b * (NB + 1) + t] = excl;
        gcursor[(size_t)b * NB + t] = excl;   // running allocation cursor
    }
    if (t == PT - 1) gofs[(size_t)b * (NB + 1) + NB] = incl;
}

// pass B (R9): LDS histogram, one block scan, atomic cursor claim per bin,
// rank+stage bin-sorted in LDS, coalesced stream-out. No cross-chunk math.
__device__ __forceinline__ void scatter_body(
    const int* __restrict__ ei, const float* __restrict__ ea,
    int* __restrict__ gcursor, int2* __restrict__ cpairs,
    int E, int NB, int CPG, int b, int c,
    int2* __restrict__ stg, int* __restrict__ lc, int* __restrict__ lstart,
    int* __restrict__ gbase, int* __restrict__ ts) {
    int t = threadIdx.x;
    int e0 = c * PCHUNK, end = min(e0 + PCHUNK, E);
    const int* srow = ei + (size_t)b * 2 * E;
    const int* drow = srow + E;

    for (int i = t; i < NB; i += PT) lc[i] = 0;
    __syncthreads();

    // local histogram
    for (int e = e0 + t; e < end; e += PT)
        atomicAdd(&lc[drow[e] >> 7], 1);
    __syncthreads();

    // block scan lc -> lstart (within-chunk staging layout)
    int v = (t < NB) ? lc[t] : 0;
    ts[t] = v;
    __syncthreads();
    int incl = v;
    for (int off = 1; off < PT; off <<= 1) {
        int add = (t >= off) ? ts[t - off] : 0;
        __syncthreads();
        incl += add;
        ts[t] = incl;
        __syncthreads();
    }
    if (t < NB) {
        lstart[t] = incl - v;
        // claim this chunk's run in the bucket's dense range (any order ok)
        if (v > 0) gbase[t] = atomicAdd(&gcursor[(size_t)b * NB + t], v);
        lc[t] = 0;
    }
    __syncthreads();

    // rank + stage into LDS (bin rides in bits 23..30; src 0-15; dl 16-22)
#pragma unroll
    for (int j = 0; j < PCHUNK / PT; ++j) {
        int e = e0 + j * PT + t;
        if (e < end) {
            int d = drow[e];
            int bin = d >> 7;
            int r = atomicAdd(&lc[bin], 1);
            stg[lstart[bin] + r] =
                make_int2(srow[e] | ((d & 127) << 16) | (bin << 23),
                          __float_as_int(ea[(size_t)b * E + e]));
        }
    }
    __syncthreads();

    // stream staged buffer out: consecutive k -> contiguous dest per run
    int total = end - e0;
    int2* cp = cpairs + (size_t)b * E;
    for (int k = t; k < total; k += PT) {
        int2 pv = stg[k];
        int bin = (pv.x >> 23) & 255;
        cp[gbase[bin] + (k - lstart[bin])] = pv;
    }
}

__device__ __forceinline__ void conv_edge_compute(
    const float* we, const float* bb, const float* __restrict__ W2,
    int2 p, int4 raw, const float* __restrict__ a1s,
    unsigned int* __restrict__ acc) {
    int dl = (p.x >> 16) & 127;
    float eav = __int_as_float(p.y);
    unsigned int wq[4] = {(unsigned int)raw.x, (unsigned int)raw.y,
                          (unsigned int)raw.z, (unsigned int)raw.w};
    float a2v[8];
#pragma unroll
    for (int q = 0; q < 4; ++q) {
        a2v[2 * q]     = __uint_as_float(wq[q] << 16);
        a2v[2 * q + 1] = __uint_as_float(wq[q] & 0xFFFF0000u);
    }
    float h1[8];
#pragma unroll
    for (int j = 0; j < 8; ++j) {
        h1[j] = a1s[dl * 9 + j] + a2v[j];
        h1[j] = fmaf(eav, we[j], h1[j]);
        h1[j] = lrelu(h1[j]);
    }
    float h2[8];
#pragma unroll
    for (int j = 0; j < 8; ++j) h2[j] = bb[j];
#pragma unroll
    for (int kk = 0; kk < 8; ++kk) {
        float hk = h1[kk];
#pragma unroll
        for (int j = 0; j < 8; ++j) h2[j] = fmaf(hk, W2[kk * 8 + j], h2[j]);
    }
#pragma unroll
    for (int j = 0; j < 8; ++j)
        atomicMin(&acc[dl * 9 + j], fmin_encode(h2[j]));
}

// batch-4: 4 outstanding a2 gathers per wave iteration hide L2/L3 latency
__device__ __forceinline__ void conv_edges_dense(
    const unsigned short* __restrict__ a2g, const float* we, const float* bb,
    const float* __restrict__ W2, const int2* __restrict__ cpg,
    int start, int end,
    const float* __restrict__ a1s, unsigned int* __restrict__ acc) {
    int t = threadIdx.x;
    int k = start + t * 4;
    for (; k + 3 < end; k += CT * 4) {
        int2 p0 = cpg[k];
        int2 p1 = cpg[k + 1];
        int2 p2 = cpg[k + 2];
        int2 p3 = cpg[k + 3];
        int4 v0 = *(const int4*)(a2g + (size_t)(p0.x & 0xFFFF) * 8);
        int4 v1 = *(const int4*)(a2g + (size_t)(p1.x & 0xFFFF) * 8);
        int4 v2 = *(const int4*)(a2g + (size_t)(p2.x & 0xFFFF) * 8);
        int4 v3 = *(const int4*)(a2g + (size_t)(p3.x & 0xFFFF) * 8);
        conv_edge_compute(we, bb, W2, p0, v0, a1s, acc);
        conv_edge_compute(we, bb, W2, p1, v1, a1s, acc);
        conv_edge_compute(we, bb, W2, p2, v2, a1s, acc);
        conv_edge_compute(we, bb, W2, p3, v3, a1s, acc);
    }
    for (int e = k; e < end && e < k + 4; ++e) {
        int2 p = cpg[e];
        int4 v = *(const int4*)(a2g + (size_t)(p.x & 0xFFFF) * 8);
        conv_edge_compute(we, bb, W2, p, v, a1s, acc);
    }
}

__device__ __forceinline__ void conv_mid_body(
    const float* __restrict__ a1, const unsigned short* __restrict__ a2,
    const float* __restrict__ w1e, const float* __restrict__ W2,
    const float* __restrict__ b2,
    const float* __restrict__ nW1, const float* __restrict__ nb1,
    const int* __restrict__ gofs, const int2* __restrict__ cpairs,
    float* __restrict__ na1, unsigned short* __restrict__ na2,
    int N, int NB, int E, int b, int bin,
    float* __restrict__ a1s, unsigned int* __restrict__ acc) {
    int n0 = bin << 7;
    int nCnt = min(BS, N - n0);
    int t = threadIdx.x;
    size_t node0 = (size_t)b * N + n0;

    for (int i = t; i < nCnt * 8; i += CT)
        a1s[(i >> 3) * 9 + (i & 7)] = a1[node0 * 8 + i];
    for (int i = t; i < BS * 9; i += CT) acc[i] = 0xFFFFFFFFu;
    float we[8], bb[8];
#pragma unroll
    for (int j = 0; j < 8; ++j) { we[j] = w1e[j]; bb[j] = b2[j]; }
    const int* gofsb = gofs + (size_t)b * (NB + 1);
    int start = gofsb[bin];
    int end = gofsb[bin + 1];
    __syncthreads();

    conv_edges_dense(a2 + (size_t)b * N * 8, we, bb, W2,
                     cpairs + (size_t)b * E, start, end, a1s, acc);
    __syncthreads();

    for (int i = t; i < nCnt * 8; i += CT) {
        float v = fmin_decode(acc[(i >> 3) * 9 + (i & 7)]);
        unsigned int u = __float_as_uint(v);
        if ((u & 0x7F800000u) == 0x7F800000u) v = 0.f;
        a1s[(i >> 3) * 9 + (i & 7)] = lrelu(v);
    }
    __syncthreads();

    for (int nh = t; nh < nCnt * 2; nh += CT) {
        int node = nh >> 1, half = nh & 1;
        float h[8];
#pragma unroll
        for (int j = 0; j < 8; ++j) h[j] = a1s[node * 9 + j];
        float v[8];
#pragma unroll
        for (int j = 0; j < 8; ++j) v[j] = half ? 0.f : nb1[j];
        const float* Wbase = nW1 + (half ? 64 : 0);
#pragma unroll
        for (int k = 0; k < 8; ++k) {
            float hk = h[k];
#pragma unroll
            for (int j = 0; j < 8; ++j) v[j] = fmaf(hk, Wbase[k * 8 + j], v[j]);
        }
        if (half) {
            unsigned int w[4];
#pragma unroll
            for (int q = 0; q < 4; ++q)
                w[q] = bf16_rne(v[2 * q]) | (bf16_rne(v[2 * q + 1]) << 16);
            *(int4*)(na2 + (node0 + node) * 8) = make_int4(w[0], w[1], w[2], w[3]);
        } else {
            float4* o = (float4*)(na1 + (node0 + node) * 8);
            o[0] = make_float4(v[0], v[1], v[2], v[3]);
            o[1] = make_float4(v[4], v[5], v[6], v[7]);
        }
    }
    __syncthreads();
}

__device__ __forceinline__ void conv_final_body(
    const float* __restrict__ a1, const unsigned short* __restrict__ a2,
    const float* __restrict__ w1e, const float* __restrict__ W2,
    const float* __restrict__ b2, const float* __restrict__ lw,
    const int* __restrict__ gofs, const int2* __restrict__ cpairs,
    float* __restrict__ out, int N, int NB, int E, int b, int bin,
    float* __restrict__ a1s, unsigned int* __restrict__ acc) {
    int n0 = bin << 7;
    int nCnt = min(BS, N - n0);
    int t = threadIdx.x;
    size_t node0 = (size_t)b * N + n0;

    for (int i = t; i < nCnt * 8; i += CT)
        a1s[(i >> 3) * 9 + (i & 7)] = a1[node0 * 8 + i];
    for (int i = t; i < BS * 9; i += CT) acc[i] = 0xFFFFFFFFu;
    float we[8], bb[8];
#pragma unroll
    for (int j = 0; j < 8; ++j) { we[j] = w1e[j]; bb[j] = b2[j]; }
    const int* gofsb = gofs + (size_t)b * (NB + 1);
    int start = gofsb[bin];
    int end = gofsb[bin + 1];
    __syncthreads();

    conv_edges_dense(a2 + (size_t)b * N * 8, we, bb, W2,
                     cpairs + (size_t)b * E, start, end, a1s, acc);
    __syncthreads();

    float c = 0.f;
    if (t < nCnt) {
#pragma unroll
        for (int j = 0; j < 8; ++j) {
            float v = fmin_decode(acc[t * 9 + j]);
            unsigned int u = __float_as_uint(v);
            if ((u & 0x7F800000u) == 0x7F800000u) v = 0.f;
            c = fmaf(lrelu(v), lw[3 + j], c);
        }
    }
    __syncthreads();
    block_add(c, &out[b]);
}

// ---------------------------------------------------------------------------
// kernels
// ---------------------------------------------------------------------------

__global__ __launch_bounds__(PT) void count_init_kernel(
    const int* __restrict__ ei, int* __restrict__ gtot,
    const int* __restrict__ nf, const float* __restrict__ act,
    const float* __restrict__ W1, const float* __restrict__ b1,
    const float* __restrict__ lw, const float* __restrict__ lb,
    float* __restrict__ a1, unsigned short* __restrict__ a2,
    float* __restrict__ out, int E, int N, int NB, int CPG) {
    __shared__ int lc[MAXNB];
    int b = blockIdx.y;
    if (blockIdx.x >= CPG) {
        init_body(nf, act, W1, b1, lw, lb, a1, a2, out, N, b, blockIdx.x - CPG);
        return;
    }
    count_body(ei, gtot, E, NB, CPG, b, blockIdx.x, lc);
}

__global__ __launch_bounds__(PT) void scatter_kernel(
    const int* __restrict__ ei, const float* __restrict__ ea,
    int* __restrict__ gcursor, int2* __restrict__ cpairs,
    int E, int NB, int CPG) {
    __shared__ __align__(16) int2 stg[PCHUNK];
    __shared__ int lc[MAXNB];
    __shared__ int lstart[MAXNB];
    __shared__ int gbase[MAXNB];
    __shared__ int ts[PT];
    scatter_body(ei, ea, gcursor, cpairs, E, NB, CPG,
                 blockIdx.y, blockIdx.x, stg, lc, lstart, gbase, ts);
}

__global__ __launch_bounds__(CT) void conv_mid_kernel(
    const float* __restrict__ a1, const unsigned short* __restrict__ a2,
    const float* __restrict__ w1e, const float* __restrict__ W2,
    const float* __restrict__ b2,
    const float* __restrict__ nW1, const float* __restrict__ nb1,
    const int* __restrict__ gofs, const int2* __restrict__ cpairs,
    float* __restrict__ na1, unsigned short* __restrict__ na2,
    int N, int NB, int E) {
    __shared__ float a1s[BS * 9];
    __shared__ unsigned int acc[BS * 9];
    conv_mid_body(a1, a2, w1e, W2, b2, nW1, nb1, gofs, cpairs, na1, na2,
                  N, NB, E, blockIdx.y, blockIdx.x, a1s, acc);
}

__global__ __launch_bounds__(CT) void conv_final_kernel(
    const float* __restrict__ a1, const unsigned short* __restrict__ a2,
    const float* __restrict__ w1e, const float* __restrict__ W2,
    const float* __restrict__ b2, const float* __restrict__ lw,
    const int* __restrict__ gofs, const int2* __restrict__ cpairs,
    float* __restrict__ out, int N, int NB, int E) {
    __shared__ float a1s[BS * 9];
    __shared__ unsigned int acc[BS * 9];
    conv_final_body(a1, a2, w1e, W2, b2, lw, gofs, cpairs, out,
                    N, NB, E, blockIdx.y, blockIdx.x, a1s, acc);
}

// ---------------------------------------------------------------------------
// atomic fallback (proven path)
// ---------------------------------------------------------------------------

__global__ __launch_bounds__(256) void node_init_kernel(
    const int* __restrict__ nf, const float* __restrict__ act,
    float* __restrict__ x0, int BN) {
    int tid = blockIdx.x * blockDim.x + threadIdx.x;
    if (tid >= BN) return;
    x0[tid * 3 + 0] = (float)nf[tid * 2 + 0];
    x0[tid * 3 + 1] = (float)nf[tid * 2 + 1];
    x0[tid * 3 + 2] = act[tid];
}

template <int D>
__global__ __launch_bounds__(256) void edge_conv_kernel(
    const float* __restrict__ x, const int* __restrict__ ei,
    const float* __restrict__ ea,
    const float* __restrict__ W1, const float* __restrict__ b1,
    const float* __restrict__ W2, const float* __restrict__ b2,
    unsigned int* __restrict__ agg, int E, int N, int B) {
    int tid = blockIdx.x * blockDim.x + threadIdx.x;
    if (tid >= B * E) return;
    int b = tid / E;
    int e = tid - b * E;
    const int* eb = ei + (size_t)b * 2 * E;
    int s = eb[e];
    int d = eb[E + e];
    const float* xi = x + ((size_t)b * N + d) * D;
    const float* xj = x + ((size_t)b * N + s) * D;
    constexpr int M = 2 * D + 1;
    float m[M];
#pragma unroll
    for (int k = 0; k < D; ++k) { m[k] = xi[k]; m[D + k] = xj[k]; }
    m[2 * D] = ea[(size_t)b * E + e];
    float h1[8];
#pragma unroll
    for (int j = 0; j < 8; ++j) h1[j] = b1[j];
#pragma unroll
    for (int k = 0; k < M; ++k) {
        float mk = m[k];
#pragma unroll
        for (int j = 0; j < 8; ++j) h1[j] = fmaf(mk, W1[k * 8 + j], h1[j]);
    }
#pragma unroll
    for (int j = 0; j < 8; ++j) h1[j] = lrelu(h1[j]);
    float h2[8];
#pragma unroll
    for (int j = 0; j < 8; ++j) h2[j] = b2[j];
#pragma unroll
    for (int k = 0; k < 8; ++k) {
        float hk = h1[k];
#pragma unroll
        for (int j = 0; j < 8; ++j) h2[j] = fmaf(hk, W2[k * 8 + j], h2[j]);
    }
    unsigned int* ag = agg + ((size_t)b * N + d) * 8;
#pragma unroll
    for (int j = 0; j < 8; ++j) atomicMin(&ag[j], fmin_encode(h2[j]));
}

__global__ __launch_bounds__(256) void finalize_kernel(
    unsigned int* __restrict__ agg, int total) {
    int tid = blockIdx.x * blockDim.x + threadIdx.x;
    if (tid >= total) return;
    float v = fmin_decode(agg[tid]);
    unsigned int u = __float_as_uint(v);
    if ((u & 0x7F800000u) == 0x7F800000u) v = 0.f;
    ((float*)agg)[tid] = lrelu(v);
}

__global__ __launch_bounds__(256) void pool_kernel(
    const float* __restrict__ x0, const float* __restrict__ h,
    const float* __restrict__ lw, const float* __restrict__ lb,
    float* __restrict__ out, int N) {
    int b = blockIdx.y;
    int n = blockIdx.x * blockDim.x + threadIdx.x;
    float c = 0.f;
    if (n < N) {
        const float* x = x0 + ((size_t)b * N + n) * 3;
        const float* hh = h + ((size_t)b * N + n) * 8;
        c = x[0] * lw[0] + x[1] * lw[1] + x[2] * lw[2];
#pragma unroll
        for (int k = 0; k < 8; ++k) c = fmaf(hh[k], lw[3 + k], c);
        if (n == 0) c += lb[0];
    }
    block_add(c, &out[b]);
}

// ---------------------------------------------------------------------------

static inline size_t align256(size_t x) { return (x + 255) & ~(size_t)255; }

extern "C" void kernel_launch(void* const* d_in, const int* in_sizes, int n_in,
                              void* d_out, int out_size, void* d_ws, size_t ws_size,
                              hipStream_t stream) {
    const int B = 4;
    const int N = in_sizes[1] / B;            // actions [B,N]
    const int E = in_sizes[2] / (2 * B);      // edge_index [B,2,E]

    const int*   nf  = (const int*)d_in[0];
    const float* act = (const float*)d_in[1];
    const int*   ei  = (const int*)d_in[2];   // int32 (JAX x64 disabled)
    const float* ea  = (const float*)d_in[3];
    const float* c1_W1 = (const float*)d_in[4];
    const float* c1_b1 = (const float*)d_in[5];
    const float* c1_W2 = (const float*)d_in[6];
    const float* c1_b2 = (const float*)d_in[7];
    const float* c2_W1 = (const float*)d_in[8];
    const float* c2_b1 = (const float*)d_in[9];
    const float* c2_W2 = (const float*)d_in[10];
    const float* c2_b2 = (const float*)d_in[11];
    const float* c3_W1 = (const float*)d_in[12];
    const float* c3_b1 = (const float*)d_in[13];
    const float* c3_W2 = (const float*)d_in[14];
    const float* c3_b2 = (const float*)d_in[15];
    const float* lw    = (const float*)d_in[16];
    const float* lb    = (const float*)d_in[17];
    float* out = (float*)d_out;

    const int BN = B * N;
    const int BE = B * E;
    const int NB = (N + BS - 1) / BS;
    const int CPG = (E + PCHUNK - 1) / PCHUNK;
    const int initBlocks = (N + PT - 1) / PT;

    // ---- workspace layout ----
    char* ws = (char*)d_ws;
    size_t off = 0;
    float* a1A = (float*)(ws + off);           off += align256((size_t)BN * 8 * 4);
    float* a1B = (float*)(ws + off);           off += align256((size_t)BN * 8 * 4);
    unsigned short* a2A = (unsigned short*)(ws + off); off += align256((size_t)BN * 8 * 2);
    unsigned short* a2B = (unsigned short*)(ws + off); off += align256((size_t)BN * 8 * 2);
    int* gtot    = (int*)(ws + off);   off += align256((size_t)B * NB * 4);
    int* gcursor = (int*)(ws + off);   off += align256((size_t)B * NB * 4);
    int2* cpairs = (int2*)(ws + off);  off += align256((size_t)BE * 8);
    int* gofs   = (int*)(ws + off);    off += align256((size_t)B * (NB + 1) * 4);
    float* x0   = (float*)(ws + off);  off += align256((size_t)BN * 3 * 4);
    const bool useFast = (off <= ws_size) && (NB <= MAXNB) && (CPG <= CPGMAX) &&
                         (N <= 32768);

    hipMemsetAsync(out, 0, (size_t)B * sizeof(float), stream);

    if (useFast) {
        hipMemsetAsync(gtot, 0, (size_t)B * NB * sizeof(int), stream);
        dim3 pgrid(CPG + initBlocks, B);
        dim3 sgrid(CPG, B);
        dim3 cgrid(NB, B);
        count_init_kernel<<<pgrid, PT, 0, stream>>>(
            ei, gtot, nf, act, c1_W1, c1_b1, lw, lb, a1A, a2A, out,
            E, N, NB, CPG);
        scan_kernel<<<B, PT, 0, stream>>>(gtot, gofs, gcursor, NB);
        scatter_kernel<<<sgrid, PT, 0, stream>>>(
            ei, ea, gcursor, cpairs, E, NB, CPG);
        conv_mid_kernel<<<cgrid, CT, 0, stream>>>(
            a1A, a2A, c1_W1 + 6 * 8, c1_W2, c1_b2, c2_W1, c2_b1,
            gofs, cpairs, a1B, a2B, N, NB, E);
        conv_mid_kernel<<<cgrid, CT, 0, stream>>>(
            a1B, a2B, c2_W1 + 16 * 8, c2_W2, c2_b2, c3_W1, c3_b1,
            gofs, cpairs, a1A, a2A, N, NB, E);
        conv_final_kernel<<<cgrid, CT, 0, stream>>>(
            a1A, a2A, c3_W1 + 16 * 8, c3_W2, c3_b2, lw,
            gofs, cpairs, out, N, NB, E);
    } else {
        // ---- atomic fallback ----
        const int egrid = (BE + 255) / 256;
        const int aggTotal = BN * 8;
        const int agrid = (aggTotal + 255) / 256;
        const size_t aggBytes = (size_t)aggTotal * 4;
        unsigned int* uA = (unsigned int*)a1A;
        unsigned int* uB = (unsigned int*)a1B;

        node_init_kernel<<<(BN + 255) / 256, 256, 0, stream>>>(nf, act, x0, BN);

        hipMemsetAsync(uA, 0xFF, aggBytes, stream);
        edge_conv_kernel<3><<<egrid, 256, 0, stream>>>(
            x0, ei, ea, c1_W1, c1_b1, c1_W2, c1_b2, uA, E, N, B);
        finalize_kernel<<<agrid, 256, 0, stream>>>(uA, aggTotal);

        hipMemsetAsync(uB, 0xFF, aggBytes, stream);
        edge_conv_kernel<8><<<egrid, 256, 0, stream>>>(
            (const float*)uA, ei, ea, c2_W1, c2_b1, c2_W2, c2_b2, uB, E, N, B);
        finalize_kernel<<<agrid, 256, 0, stream>>>(uB, aggTotal);

        hipMemsetAsync(uA, 0xFF, aggBytes, stream);
        edge_conv_kernel<8><<<egrid, 256, 0, stream>>>(
            (const float*)uB, ei, ea, c3_W1, c3_b1, c3_W2, c3_b2, uA, E, N, B);
        finalize_kernel<<<agrid, 256, 0, stream>>>(uA, aggTotal);

        dim3 plgrid((N + 255) / 256, B);
        pool_kernel<<<plgrid, 256, 0, stream>>>(x0, (const float*)uA, lw, lb, out, N);
    }
}